// Round 3
// baseline (445.688 us; speedup 1.0000x reference)
//
#include <hip/hip_runtime.h>
#include <cstdint>
#include <cstddef>

#define B_  64
#define D_  1024
#define S_  512
#define K_  100
#define KP_ 128
#define H_  2048
#define BS_ (B_*S_)   // 32768

// ---- workspace layout (float offsets) ----
static constexpr size_t OFF_TVN  = 0;                          // [1024][128] padded normalized topics
static constexpr size_t OFF_TPNT = 131072;                     // [100][32768] topic_prob_n transposed
static constexpr size_t OFF_HSUM = OFF_TPNT + (size_t)K_*BS_;  // [64][2048]
static constexpr size_t OFF_INTS = OFF_HSUM + (size_t)B_*H_;   // int region: cnt, bact[64], alist[32768]

#define GLOAD_LDS16(g, l) __builtin_amdgcn_global_load_lds( \
    (const __attribute__((address_space(1))) void*)(g), \
    (__attribute__((address_space(3))) void*)(l), 16, 0, 0)

// ---------------------------------------------------------------------------
// prep: blocks 0..127 normalize topic columns -> tvn[1024][128] (pad cols 0);
//       blocks 128..639 zero hsum; block 640: out scalar init + ints zero.
__global__ __launch_bounds__(256) void prep_kernel(
    const float* __restrict__ tv, const float* __restrict__ bc,
    float* __restrict__ tvn, float* __restrict__ hsum,
    int* __restrict__ ints, float* __restrict__ out)
{
    __shared__ float red[256];
    const int tid = threadIdx.x;
    const int blk = blockIdx.x;
    if (blk < KP_) {
        const int k = blk;
        if (k >= K_) {
            for (int d = tid; d < D_; d += 256) tvn[d*KP_ + k] = 0.f;
            return;
        }
        float ss = 0.f;
        for (int d = tid; d < D_; d += 256) { float v = tv[d*K_ + k]; ss = fmaf(v, v, ss); }
        red[tid] = ss;
        __syncthreads();
        for (int s = 128; s > 0; s >>= 1) {
            if (tid < s) red[tid] += red[tid + s];
            __syncthreads();
        }
        const float inv = 1.0f / fmaxf(sqrtf(red[0]), 1e-12f);
        for (int d = tid; d < D_; d += 256) tvn[d*KP_ + k] = tv[d*K_ + k] * inv;
        return;
    }
    if (blk < KP_ + 512) {
        hsum[(blk - KP_)*256 + tid] = 0.f;       // 512*256 == B_*H_
        return;
    }
    // scalar init block
    if (tid < 128)      out[tid] = bc[tid & 1];  // pred = b_cls (atomics add partials)
    else if (tid < 131) out[tid] = 0.f;          // out[128]=0, sim=0 (+atomics), far placeholder
    if (tid < 65) ints[tid] = 0;                 // cnt + bact[64]
}

// ---------------------------------------------------------------------------
// gemm1: topic_prob = f^T . tvn  (fp32 VALU GEMM), plus row norms, mask,
// nn (-> d_out), tpn^T (-> ws), active-row list.
// Grid 512 = 64 b x 8 s-tiles(64). Block 128 threads (2 waves).
// Per-thread tile 8s x 8k: 4 ds_read_b128 per 64 FMAs.
// f staged via registers (row-norms come free); tvn staged via global_load_lds.
__global__ __launch_bounds__(128, 2) void gemm1_kernel(
    const float* __restrict__ f, const float* __restrict__ tvn,
    float* __restrict__ out_nn, float* __restrict__ tpnT,
    int* __restrict__ cnt, int* __restrict__ bact, int* __restrict__ alist)
{
    __shared__ __align__(16) float fs[2][32*64];    // 16 KiB  (fs[0] reused as epilogue scratch)
    __shared__ __align__(16) float ts[2][32*128];   // 32 KiB
    __shared__ float ninv[64];
    __shared__ float rinv[64];

    const int tid  = threadIdx.x;
    const int lane = tid & 63;
    const int wv   = tid >> 6;            // wave 0/1
    const int b    = blockIdx.x >> 3;
    const int s0   = (blockIdx.x & 7) << 6;

    // f staging map: rows fr+8i (i=0..3), col quad fc
    const int fr = tid >> 4;              // 0..7
    const int fc = (tid & 15) << 2;       // 0..60
    // compute map: 8 s-groups x 16 k-groups
    const int sg = tid & 7;               // s = sg*8 + r
    const int kg = tid >> 3;              // k = kg*8 + j

    const float* fb = f + (size_t)b * D_ * S_ + s0;

    float acc[8][8];
#pragma unroll
    for (int r = 0; r < 8; ++r)
#pragma unroll
        for (int j = 0; j < 8; ++j) acc[r][j] = 0.f;
    float nsq[4] = {0.f, 0.f, 0.f, 0.f};

    float4 rf[4];
    // ---- prologue: stage step 0 ----
#pragma unroll
    for (int i = 0; i < 4; ++i)
        rf[i] = *(const float4*)(fb + (size_t)(fr + 8*i) * S_ + fc);
#pragma unroll
    for (int i = 0; i < 8; ++i) {
        const int c = wv*8 + i;
        GLOAD_LDS16(tvn + c*256 + lane*4, &ts[0][c*256]);
    }
#pragma unroll
    for (int i = 0; i < 4; ++i) {
        *(float4*)&fs[0][(fr + 8*i)*64 + fc] = rf[i];
        nsq[0] = fmaf(rf[i].x, rf[i].x, nsq[0]);
        nsq[1] = fmaf(rf[i].y, rf[i].y, nsq[1]);
        nsq[2] = fmaf(rf[i].z, rf[i].z, nsq[2]);
        nsq[3] = fmaf(rf[i].w, rf[i].w, nsq[3]);
    }

    for (int step = 0; step < 32; ++step) {
        const int cur = step & 1;
        __syncthreads();                  // fs[cur] writes visible + ts[cur] vm drained
        if (step < 31) {                  // issue next-step loads AFTER barrier -> overlap compute
            const int d0 = (step + 1) << 5;
#pragma unroll
            for (int i = 0; i < 4; ++i)
                rf[i] = *(const float4*)(fb + (size_t)(d0 + fr + 8*i) * S_ + fc);
            const float* tsrc = tvn + (size_t)d0 * KP_;
#pragma unroll
            for (int i = 0; i < 8; ++i) {
                const int c = wv*8 + i;
                GLOAD_LDS16(tsrc + c*256 + lane*4, &ts[cur ^ 1][c*256]);
            }
        }
        const float* fcur = fs[cur];
        const float* tcur = ts[cur];
#pragma unroll 8
        for (int di = 0; di < 32; ++di) {
            const float4 a0 = *(const float4*)&fcur[di*64 + sg*8];
            const float4 a1 = *(const float4*)&fcur[di*64 + sg*8 + 4];
            const float4 w0 = *(const float4*)&tcur[di*128 + kg*8];
            const float4 w1 = *(const float4*)&tcur[di*128 + kg*8 + 4];
            const float a[8] = {a0.x,a0.y,a0.z,a0.w,a1.x,a1.y,a1.z,a1.w};
            const float w[8] = {w0.x,w0.y,w0.z,w0.w,w1.x,w1.y,w1.z,w1.w};
#pragma unroll
            for (int r = 0; r < 8; ++r)
#pragma unroll
                for (int j = 0; j < 8; ++j)
                    acc[r][j] = fmaf(a[r], w[j], acc[r][j]);
        }
        if (step < 31) {
#pragma unroll
            for (int i = 0; i < 4; ++i) {
                *(float4*)&fs[cur ^ 1][(fr + 8*i)*64 + fc] = rf[i];
                nsq[0] = fmaf(rf[i].x, rf[i].x, nsq[0]);
                nsq[1] = fmaf(rf[i].y, rf[i].y, nsq[1]);
                nsq[2] = fmaf(rf[i].z, rf[i].z, nsq[2]);
                nsq[3] = fmaf(rf[i].w, rf[i].w, nsq[3]);
            }
        }
    }

    // ---- epilogue ----
    float* red = &fs[0][0];               // scratch (all fs[0] readers done: last read was step 30)
    __syncthreads();
    red[fr*64 + fc + 0] = nsq[0];
    red[fr*64 + fc + 1] = nsq[1];
    red[fr*64 + fc + 2] = nsq[2];
    red[fr*64 + fc + 3] = nsq[3];
    __syncthreads();
    if (tid < 64) {
        float t = 0.f;
#pragma unroll
        for (int g = 0; g < 8; ++g) t += red[g*64 + tid];
        ninv[tid] = 1.0f / fmaxf(sqrtf(t), 1e-12f);
    }
    __syncthreads();

    const int bs0 = b * S_ + s0;
    float inv_s[8];
#pragma unroll
    for (int r = 0; r < 8; ++r) inv_s[r] = ninv[sg*8 + r];

    float rowp[8];
#pragma unroll
    for (int r = 0; r < 8; ++r) rowp[r] = 0.f;

#pragma unroll
    for (int j = 0; j < 8; ++j) {
        const int k = kg*8 + j;
        float tq[8];
#pragma unroll
        for (int r = 0; r < 8; ++r) tq[r] = acc[r][j] * inv_s[r];
#pragma unroll
        for (int r = 0; r < 8; ++r) {
            acc[r][j] = (tq[r] > 0.3f) ? acc[r][j] : 0.f;   // topic_prob * mask
            rowp[r] += acc[r][j];
        }
        if (k < K_) {                     // topic_prob_n transposed (coalesced float4 pairs)
            float4 v0; v0.x = tq[0]; v0.y = tq[1]; v0.z = tq[2]; v0.w = tq[3];
            float4 v1; v1.x = tq[4]; v1.y = tq[5]; v1.z = tq[6]; v1.w = tq[7];
            float* dst = tpnT + (size_t)k * BS_ + bs0 + sg*8;
            *(float4*)dst = v0;
            *(float4*)(dst + 4) = v1;
        }
    }

    __syncthreads();                      // norm-scratch reads done; reuse red for rowsum
#pragma unroll
    for (int r = 0; r < 8; ++r) red[kg*64 + sg*8 + r] = rowp[r];
    __syncthreads();
    if (tid < 64) {
        float t = 0.f;
#pragma unroll
        for (int g = 0; g < 16; ++g) t += red[g*64 + tid];
        rinv[tid] = 1.0f / (t + 0.001f);
        if (t > 0.f) {                    // any unmasked concept in this row
            const int pos = atomicAdd(cnt, 1);
            alist[pos] = bs0 + tid;
            atomicAdd(&bact[b], 1);
        }
    }
    __syncthreads();
    float rs[8];
#pragma unroll
    for (int r = 0; r < 8; ++r) rs[r] = rinv[sg*8 + r];
    float* ob = out_nn + (size_t)bs0 * K_;
#pragma unroll
    for (int j = 0; j < 8; ++j) {
        const int k = kg*8 + j;
        if (k < K_) {
#pragma unroll
            for (int r = 0; r < 8; ++r)
                ob[(size_t)(sg*8 + r) * K_ + k] = acc[r][j] * rs[r];
        }
    }
}

// ---------------------------------------------------------------------------
// gemm2p: blocks 0..127 sparse rec1 accumulation over active rows;
//         block 128 computes concept_far -> out[130].
__global__ __launch_bounds__(256) void gemm2p_kernel(
    const float* __restrict__ nn, const float* __restrict__ W1,
    float* __restrict__ hsum, const int* __restrict__ cnt,
    const int* __restrict__ alist, const float* __restrict__ tvn,
    float* __restrict__ out)
{
    __shared__ float red[256];
    const int tid = threadIdx.x;
    if (blockIdx.x == 128) {              // concept_far = (||sum_k tvn_col||^2 - K)/K^2
        float part = 0.f;
        for (int d = tid; d < D_; d += 256) {
            const float4* row = (const float4*)(tvn + (size_t)d * KP_);
            float s = 0.f;
#pragma unroll 8
            for (int i = 0; i < 32; ++i) { float4 v = row[i]; s += v.x + v.y + v.z + v.w; }
            part = fmaf(s, s, part);
        }
        red[tid] = part;
        __syncthreads();
        for (int s = 128; s > 0; s >>= 1) {
            if (tid < s) red[tid] += red[tid + s];
            __syncthreads();
        }
        if (tid == 0) out[130] = (red[0] - (float)K_) / ((float)K_ * (float)K_);
        return;
    }
    __shared__ float nl[K_];
    const int n = *cnt;
    for (int idx = blockIdx.x; idx < n; idx += 128) {
        const int bs = alist[idx];
        const int b  = bs >> 9;
        __syncthreads();
        if (tid < K_) nl[tid] = nn[(size_t)bs * K_ + tid];
        __syncthreads();
        for (int h = tid; h < H_; h += 256) {
            float a = 0.f;
#pragma unroll 4
            for (int k = 0; k < K_; ++k) a = fmaf(nl[k], W1[k*H_ + h], a);
            atomicAdd(&hsum[(size_t)b*H_ + h], fmaxf(a, 0.f));
        }
    }
}

// ---------------------------------------------------------------------------
// gemm3p: feat = (hsum . W2)/S fused into pred partial atomics.
// Inactive batch (the common case) -> immediate exit, pred stays b_cls.
__global__ __launch_bounds__(256) void gemm3p_kernel(
    const float* __restrict__ hsum, const float* __restrict__ W2,
    const float* __restrict__ Wc, const int* __restrict__ bact,
    float* __restrict__ out)
{
    const int b = blockIdx.x >> 2;
    if (bact[b] == 0) return;
    __shared__ float hl[H_];
    __shared__ float red[256];
    const int tid = threadIdx.x;
    const int d = ((blockIdx.x & 3) << 8) + tid;
    for (int h = tid; h < H_; h += 256) hl[h] = hsum[(size_t)b*H_ + h];
    __syncthreads();
    float a = 0.f;
    for (int h = 0; h < H_; ++h) a = fmaf(hl[h], W2[(size_t)h*D_ + d], a);
    a *= (1.0f/512.0f);                   // feat[b][d]
    const float p0 = a * Wc[d*2];
    const float p1 = a * Wc[d*2 + 1];
    red[tid] = p0;
    __syncthreads();
    for (int s = 128; s > 0; s >>= 1) {
        if (tid < s) red[tid] += red[tid + s];
        __syncthreads();
    }
    if (tid == 0) atomicAdd(&out[b*2], red[0]);
    __syncthreads();
    red[tid] = p1;
    __syncthreads();
    for (int s = 128; s > 0; s >>= 1) {
        if (tid < s) red[tid] += red[tid + s];
        __syncthreads();
    }
    if (tid == 0) atomicAdd(&out[b*2 + 1], red[0]);
}

// ---------------------------------------------------------------------------
// topk: per-concept top-16 sum over 32768; per-thread register top16 +
// register/shuffle tournament merge (no LDS candidate array).
// Adds -sum/1600 into out[129].
__global__ __launch_bounds__(256) void topk_kernel(const float* __restrict__ tpnT,
                                                   float* __restrict__ out)
{
    __shared__ float wvv[4];
    __shared__ int   wvi[4];
    const int tid = threadIdx.x;
    const int k = blockIdx.x;
    const float* col = tpnT + (size_t)k * BS_;
    float lst[16];
#pragma unroll
    for (int q = 0; q < 16; ++q) lst[q] = -3.4e38f;
    for (int i = tid; i < BS_; i += 256) {
        const float v = col[i];
        if (v > lst[0]) {                 // insert keeping ascending order
            float nl[16];
#pragma unroll
            for (int q = 0; q < 16; ++q) {
                const bool sh = (q < 15) ? (lst[q+1] < v) : false;
                nl[q] = sh ? lst[q+1] : ((lst[q] < v) ? v : lst[q]);
            }
#pragma unroll
            for (int q = 0; q < 16; ++q) lst[q] = nl[q];
        }
    }
    float sum = 0.f;
    for (int r = 0; r < 16; ++r) {
        float m = lst[0]; int mi = 0;
#pragma unroll
        for (int q = 1; q < 16; ++q) if (lst[q] > m) { m = lst[q]; mi = q; }
        int idx = (tid << 4) | mi;
        for (int off = 32; off > 0; off >>= 1) {
            const float om = __shfl_xor(m, off);
            const int   oi = __shfl_xor(idx, off);
            if (om > m) { m = om; idx = oi; }
        }
        if ((tid & 63) == 0) { wvv[tid >> 6] = m; wvi[tid >> 6] = idx; }
        __syncthreads();
        float gm = wvv[0]; int gi = wvi[0];
#pragma unroll
        for (int w = 1; w < 4; ++w) if (wvv[w] > gm) { gm = wvv[w]; gi = wvi[w]; }
        sum += gm;
        if (tid == (gi >> 4)) {
            const int cq = gi & 15;
#pragma unroll
            for (int q = 0; q < 16; ++q) if (q == cq) lst[q] = -3.4e38f;
        }
        __syncthreads();
    }
    if (tid == 0) atomicAdd(&out[129], sum * (-1.0f/1600.0f));
}

// ---------------------------------------------------------------------------
extern "C" void kernel_launch(void* const* d_in, const int* in_sizes, int n_in,
                              void* d_out, int out_size, void* d_ws, size_t ws_size,
                              hipStream_t stream)
{
    (void)in_sizes; (void)n_in; (void)out_size; (void)ws_size;
    const float* f   = (const float*)d_in[0];
    const float* tv  = (const float*)d_in[1];
    const float* W1  = (const float*)d_in[2];
    const float* W2  = (const float*)d_in[3];
    const float* Wc  = (const float*)d_in[4];
    const float* bc  = (const float*)d_in[5];
    float* out = (float*)d_out;
    float* ws  = (float*)d_ws;

    float* tvn  = ws + OFF_TVN;
    float* tpnT = ws + OFF_TPNT;
    float* hsum = ws + OFF_HSUM;
    int*   ints = (int*)(ws + OFF_INTS);
    int* cnt   = ints;
    int* bact  = ints + 1;
    int* alist = ints + 65;
    float* out_nn = out + 131;

    hipLaunchKernelGGL(prep_kernel,   dim3(641), dim3(256), 0, stream, tv, bc, tvn, hsum, ints, out);
    hipLaunchKernelGGL(gemm1_kernel,  dim3(512), dim3(128), 0, stream, f, tvn, out_nn, tpnT, cnt, bact, alist);
    hipLaunchKernelGGL(gemm2p_kernel, dim3(129), dim3(256), 0, stream, out_nn, W1, hsum, cnt, alist, tvn, out);
    hipLaunchKernelGGL(gemm3p_kernel, dim3(256), dim3(256), 0, stream, hsum, W2, Wc, bact, out);
    hipLaunchKernelGGL(topk_kernel,   dim3(K_),  dim3(256), 0, stream, tpnT, out);
}